// Round 6
// baseline (304.565 us; speedup 1.0000x reference)
//
#include <hip/hip_runtime.h>
#include <float.h>
#include <math.h>

#define EPS 1e-6f

typedef __attribute__((ext_vector_type(8))) short short8;   // 8 bf16 = 4 VGPR
typedef __attribute__((ext_vector_type(4))) float f32x4;

constexpr int Nn = 8192;   // B*H*W
constexpr int Dd = 64;
constexpr int Kk = 8192;
constexpr int PLANE = Nn * Dd;
constexpr int KSPLIT = 32;
constexpr int KPB = Kk / KSPLIT;          // 256 codewords per strip
constexpr int NT = KPB / 16;              // 16 tiles per strip
constexpr int TILE_USH = 6 * 64 * 8;      // 3072 ushort per 16-codeword tile

// exact 3-way bf16 split: v == f(h1)+f(h2)+f(h3) (24 mantissa bits, lossless)
__device__ __forceinline__ void split3(float v, unsigned short& h1, unsigned short& h2, unsigned short& h3) {
    unsigned u = __float_as_uint(v);
    h1 = (unsigned short)(u >> 16);
    float r1 = v - __uint_as_float((unsigned)h1 << 16);
    h2 = (unsigned short)(__float_as_uint(r1) >> 16);
    float r2 = r1 - __uint_as_float((unsigned)h2 << 16);
    h3 = (unsigned short)(__float_as_uint(r2) >> 16);
}

// ---- prep ----
// e -> es_t tiled-fragment layout + en2h + et (fp32 [k][d] transpose)
// x -> xs row-major planes + xn2
__global__ void prep_kernel(const float* __restrict__ e, const float* __restrict__ x,
                            unsigned short* __restrict__ es_t, float* __restrict__ en2h,
                            float* __restrict__ et,
                            unsigned short* __restrict__ xs, float* __restrict__ xn2)
{
    const int tid = threadIdx.x;
    if (blockIdx.x < 32) {
        const int k = blockIdx.x * 256 + tid;
        const int t = k >> 4, l15 = k & 15;
        unsigned short* tb = es_t + (size_t)t * TILE_USH;
        float s = 0.f;
        #pragma unroll
        for (int c = 0; c < 8; ++c) {          // c = ks*4 + kg ; d = c*8 + j
            const int ks = c >> 2, kg = c & 3;
            short8 h1v, h2v, h3v;
            float fv[8];
            #pragma unroll
            for (int j = 0; j < 8; ++j) {
                float v = e[(c * 8 + j) * Kk + k];
                fv[j] = v;
                s = fmaf(v, v, s);
                unsigned short h1, h2, h3; split3(v, h1, h2, h3);
                h1v[j] = (short)h1; h2v[j] = (short)h2; h3v[j] = (short)h3;
            }
            const int lofs = (kg * 16 + l15) * 8;
            *(short8*)(tb + (0 * 2 + ks) * 512 + lofs) = h1v;
            *(short8*)(tb + (1 * 2 + ks) * 512 + lofs) = h2v;
            *(short8*)(tb + (2 * 2 + ks) * 512 + lofs) = h3v;
            *(float4*)(et + (size_t)k * Dd + c * 8)     = *(float4*)&fv[0];
            *(float4*)(et + (size_t)k * Dd + c * 8 + 4) = *(float4*)&fv[4];
        }
        en2h[k] = 0.5f * s;
    } else {
        const int p = (blockIdx.x - 32) * 256 + tid;
        const int b = p >> 10, hw = p & 1023;
        float s = 0.f;
        #pragma unroll
        for (int c = 0; c < 8; ++c) {
            short8 h1v, h2v, h3v;
            #pragma unroll
            for (int j = 0; j < 8; ++j) {
                float v = x[(b * Dd + c * 8 + j) * 1024 + hw];
                s = fmaf(v, v, s);
                unsigned short h1, h2, h3; split3(v, h1, h2, h3);
                h1v[j] = (short)h1; h2v[j] = (short)h2; h3v[j] = (short)h3;
            }
            *(short8*)(xs + (size_t)p * Dd + c * 8) = h1v;
            *(short8*)(xs + PLANE + (size_t)p * Dd + c * 8) = h2v;
            *(short8*)(xs + 2 * PLANE + (size_t)p * Dd + c * 8) = h3v;
        }
        xn2[p] = s;
    }
}

// one 16-codeword tile: 24 MFMAs (2 m-frags x 6 products x 2 ksteps) + argmin
__device__ __forceinline__ void tile_compute(
    const short8 (&a)[2][3][2], const short8 (&b)[6], float en,
    int nb, int l15, float (&bv)[2][4], int (&bi)[2][4])
{
    f32x4 acc[2][2] = {};
    #define PROD(sx, se) \
        acc[0][0] = __builtin_amdgcn_mfma_f32_16x16x32_bf16(a[0][sx][0], b[(se)*2+0], acc[0][0], 0,0,0); \
        acc[1][0] = __builtin_amdgcn_mfma_f32_16x16x32_bf16(a[1][sx][0], b[(se)*2+0], acc[1][0], 0,0,0); \
        acc[0][1] = __builtin_amdgcn_mfma_f32_16x16x32_bf16(a[0][sx][1], b[(se)*2+1], acc[0][1], 0,0,0); \
        acc[1][1] = __builtin_amdgcn_mfma_f32_16x16x32_bf16(a[1][sx][1], b[(se)*2+1], acc[1][1], 0,0,0);
    PROD(0,0) PROD(0,1) PROD(1,0) PROD(0,2) PROD(1,1) PROD(2,0)
    #undef PROD
    #pragma unroll
    for (int mi = 0; mi < 2; ++mi)
        #pragma unroll
        for (int j = 0; j < 4; ++j) {
            float s = en - (acc[mi][0][j] + acc[mi][1][j]);   // 0.5||e||^2 - x.e
            if (s < bv[mi][j]) { bv[mi][j] = s; bi[mi][j] = nb + l15; }
        }
}

// coalesced tiled-fragment load: one base, imm frag offsets
#define LOADB(bf, env, ti) { \
    const short8* tp_ = (const short8*)(es_t + (size_t)(ti) * TILE_USH) + lane; \
    bf[0] = tp_[0];   bf[1] = tp_[64];  bf[2] = tp_[128]; \
    bf[3] = tp_[192]; bf[4] = tp_[256]; bf[5] = tp_[320]; \
    env = en2h[(ti) * 16 + l15]; }

// grid (Nn/32 = 256, KSPLIT=32), block 64 = ONE wave. Wave: 32 pixels x 256
// codewords. No LDS/barriers; single-wave blocks maximize schedulable TLP.
__global__ __launch_bounds__(64, 5) void dist_mfma(
    const unsigned short* __restrict__ xs, const unsigned short* __restrict__ es_t,
    const float* __restrict__ en2h,
    float* __restrict__ pval, int* __restrict__ pidx)
{
    const int lane = threadIdx.x & 63;
    const int l15 = lane & 15, kg = lane >> 4;
    const int m0 = blockIdx.x * 32;
    const int t0 = blockIdx.y * NT;           // first tile of this strip

    short8 a[2][3][2];
    #pragma unroll
    for (int mi = 0; mi < 2; ++mi) {
        const unsigned short* xp = xs + (size_t)(m0 + mi * 16 + l15) * Dd + kg * 8;
        #pragma unroll
        for (int s = 0; s < 3; ++s)
            #pragma unroll
            for (int ks = 0; ks < 2; ++ks)
                a[mi][s][ks] = *(const short8*)(xp + s * PLANE + ks * 32);
    }

    float bv[2][4]; int bi[2][4];
    #pragma unroll
    for (int mi = 0; mi < 2; ++mi)
        #pragma unroll
        for (int j = 0; j < 4; ++j) { bv[mi][j] = FLT_MAX; bi[mi][j] = 0; }

    short8 bA[6], bB[6]; float enA, enB;
    LOADB(bA, enA, t0)
    #pragma unroll 1
    for (int nt = 0; nt < NT; nt += 2) {
        const int ti = t0 + nt;
        LOADB(bB, enB, ti + 1)                        // prefetch odd tile
        tile_compute(a, bA, enA, ti * 16, l15, bv, bi);
        if (nt + 2 < NT) { LOADB(bA, enA, ti + 2) }   // prefetch next even tile
        tile_compute(a, bB, enB, ti * 16 + 16, l15, bv, bi);
    }

    #pragma unroll
    for (int m = 1; m < 16; m <<= 1) {
        #pragma unroll
        for (int mi = 0; mi < 2; ++mi)
            #pragma unroll
            for (int j = 0; j < 4; ++j) {
                float ov = __shfl_xor(bv[mi][j], m, 64);
                int   oi = __shfl_xor(bi[mi][j], m, 64);
                if (ov < bv[mi][j] || (ov == bv[mi][j] && oi < bi[mi][j])) {
                    bv[mi][j] = ov; bi[mi][j] = oi;
                }
            }
    }
    if (l15 == 0) {
        #pragma unroll
        for (int mi = 0; mi < 2; ++mi)
            #pragma unroll
            for (int j = 0; j < 4; ++j) {
                int pix = m0 + mi * 16 + kg * 4 + j;
                pval[pix * KSPLIT + blockIdx.y] = bv[mi][j];
                pidx[pix * KSPLIT + blockIdx.y] = bi[mi][j];
            }
    }
}

// ---- final argmin + rotation trick (affine form qd = cx*x + cq*q) ----
// grid (32, 2): 256 pixels per block, 32 d's per blockIdx.y
__global__ __launch_bounds__(256) void finalize_kernel(
    const float* __restrict__ x, const float* __restrict__ et,
    const float* __restrict__ en2h, const float* __restrict__ xn2,
    const float* __restrict__ pval, const int* __restrict__ pidx,
    float* __restrict__ out_qd, float* __restrict__ out_q, float* __restrict__ out_ind)
{
    const int tid = threadIdx.x;
    const int p = blockIdx.x * 256 + tid;

    // partials are KSPLIT consecutive per pixel -> vectorized float4/int4 reads
    const float4* pv4 = (const float4*)(pval + (size_t)p * KSPLIT);
    const int4*   pi4 = (const int4*)(pidx + (size_t)p * KSPLIT);
    float bvv = FLT_MAX; int bii = 0;
    #pragma unroll
    for (int u = 0; u < KSPLIT / 4; ++u) {
        float4 v4 = pv4[u]; int4 i4 = pi4[u];
        #pragma unroll
        for (int jj = 0; jj < 4; ++jj) {
            float v = ((const float*)&v4)[jj];
            int   i = ((const int*)&i4)[jj];
            if (v < bvv || (v == bvv && i < bii)) { bvv = v; bii = i; }
        }
    }
    if (blockIdx.y == 0) out_ind[p] = (float)bii;

    float sx2 = xn2[p];
    float enh = en2h[bii];
    float sq2 = 2.f * enh;            // ||q||^2
    float sxq = enh - bvv;            // x.q recovered from winning score
    float ne = sqrtf(sx2), nq = sqrtf(sq2);
    float inv_e = 1.f / (ne + EPS), inv_q = 1.f / (nq + EPS);
    float lmbda = (nq + EPS) * inv_e;
    float ehat_dot_e = sx2 * inv_e;
    float rn2 = sx2 * inv_e * inv_e + 2.f * sxq * inv_e * inv_q + sq2 * inv_q * inv_q;
    float inv_r = rsqrtf(rn2);
    float rde = (sx2 * inv_e + sxq * inv_q) * inv_r;
    float cx = lmbda * (1.f - 2.f * rde * inv_r * inv_e);
    float cq = 2.f * lmbda * inv_q * (ehat_dot_e - rde * inv_r);

    const int b = p >> 10, hw = p & 1023;
    const int d0 = blockIdx.y * 32;
    const float* xb = x + (b * Dd + d0) * 1024 + hw;
    const float* er = et + (size_t)bii * Dd + d0;   // consecutive per thread
    float* qd_b = out_qd + (b * Dd + d0) * 1024 + hw;
    float* q_b  = out_q  + (b * Dd + d0) * 1024 + hw;
    #pragma unroll
    for (int dv = 0; dv < 8; ++dv) {
        float4 q4 = *(const float4*)(er + dv * 4);
        #pragma unroll
        for (int jj = 0; jj < 4; ++jj) {
            int d = dv * 4 + jj;
            float xv = xb[d * 1024];
            float qv = ((const float*)&q4)[jj];
            qd_b[d * 1024] = cx * xv + cq * qv;
            q_b[d * 1024]  = qv;
        }
    }
}

extern "C" void kernel_launch(void* const* d_in, const int* in_sizes, int n_in,
                              void* d_out, int out_size, void* d_ws, size_t ws_size,
                              hipStream_t stream) {
    const float* x = (const float*)d_in[0];   // (8,64,32,32)
    const float* e = (const float*)d_in[1];   // (64,8192)
    float* out = (float*)d_out;
    float* out_qd  = out;
    float* out_q   = out + Nn * Dd;
    float* out_ind = out + 2 * Nn * Dd;

    unsigned short* xs   = (unsigned short*)d_ws;          // 3*PLANE ushort (3 MB)
    unsigned short* es_t = xs + 3 * PLANE;                 // 512*3072 ushort (3 MB)
    float* et   = (float*)(es_t + (size_t)(Kk / 16) * TILE_USH);  // Kk*Dd f32 (2 MB)
    float* en2h = et + (size_t)Kk * Dd;                    // Kk f32
    float* xn2  = en2h + Kk;                               // Nn f32
    float* pval = xn2 + Nn;                                // Nn*KSPLIT f32 (1 MB)
    int*   pidx = (int*)(pval + (size_t)Nn * KSPLIT);      // Nn*KSPLIT i32 (1 MB)

    prep_kernel<<<64, 256, 0, stream>>>(e, x, es_t, en2h, et, xs, xn2);
    dist_mfma<<<dim3(Nn / 32, KSPLIT), 64, 0, stream>>>(xs, es_t, en2h, pval, pidx);
    finalize_kernel<<<dim3(32, 2), 256, 0, stream>>>(x, et, en2h, xn2, pval, pidx,
                                                     out_qd, out_q, out_ind);
}

// Round 7
// 72.908 us; speedup vs baseline: 4.1774x; 4.1774x over previous
//
#include <hip/hip_runtime.h>
#include <float.h>
#include <math.h>

#define EPS 1e-6f

typedef __attribute__((ext_vector_type(8))) short short8;   // 8 bf16 = 4 VGPR
typedef __attribute__((ext_vector_type(4))) float f32x4;

constexpr int Nn = 8192;   // B*H*W
constexpr int Dd = 64;
constexpr int Kk = 8192;
constexpr int PLANE = Nn * Dd;
constexpr int KSPLIT = 32;
constexpr int KPB = Kk / KSPLIT;          // 256 codewords per strip
constexpr int NT = KPB / 16;              // 16 tiles per strip
constexpr int TILE_USH = 6 * 64 * 8;      // 3072 ushort per 16-codeword tile

// exact 3-way bf16 split: v == f(h1)+f(h2)+f(h3) (24 mantissa bits, lossless)
__device__ __forceinline__ void split3(float v, unsigned short& h1, unsigned short& h2, unsigned short& h3) {
    unsigned u = __float_as_uint(v);
    h1 = (unsigned short)(u >> 16);
    float r1 = v - __uint_as_float((unsigned)h1 << 16);
    h2 = (unsigned short)(__float_as_uint(r1) >> 16);
    float r2 = r1 - __uint_as_float((unsigned)h2 << 16);
    h3 = (unsigned short)(__float_as_uint(r2) >> 16);
}

// ---- prep ----
// e -> es_t tiled-fragment layout + en2h + et (fp32 [k][d] transpose)
// x -> xs row-major planes (NEGATED splits, so MFMA accumulates -x.e) + xn2
__global__ void prep_kernel(const float* __restrict__ e, const float* __restrict__ x,
                            unsigned short* __restrict__ es_t, float* __restrict__ en2h,
                            float* __restrict__ et,
                            unsigned short* __restrict__ xs, float* __restrict__ xn2)
{
    const int tid = threadIdx.x;
    if (blockIdx.x < 32) {
        const int k = blockIdx.x * 256 + tid;
        const int t = k >> 4, l15 = k & 15;
        unsigned short* tb = es_t + (size_t)t * TILE_USH;
        float s = 0.f;
        #pragma unroll
        for (int c = 0; c < 8; ++c) {          // c = ks*4 + kg ; d = c*8 + j
            const int ks = c >> 2, kg = c & 3;
            short8 h1v, h2v, h3v;
            float fv[8];
            #pragma unroll
            for (int j = 0; j < 8; ++j) {
                float v = e[(c * 8 + j) * Kk + k];
                fv[j] = v;
                s = fmaf(v, v, s);
                unsigned short h1, h2, h3; split3(v, h1, h2, h3);
                h1v[j] = (short)h1; h2v[j] = (short)h2; h3v[j] = (short)h3;
            }
            const int lofs = (kg * 16 + l15) * 8;
            *(short8*)(tb + (0 * 2 + ks) * 512 + lofs) = h1v;
            *(short8*)(tb + (1 * 2 + ks) * 512 + lofs) = h2v;
            *(short8*)(tb + (2 * 2 + ks) * 512 + lofs) = h3v;
            *(float4*)(et + (size_t)k * Dd + c * 8)     = *(float4*)&fv[0];
            *(float4*)(et + (size_t)k * Dd + c * 8 + 4) = *(float4*)&fv[4];
        }
        en2h[k] = 0.5f * s;
    } else {
        const int p = (blockIdx.x - 32) * 256 + tid;
        const int b = p >> 10, hw = p & 1023;
        float s = 0.f;
        #pragma unroll
        for (int c = 0; c < 8; ++c) {
            short8 h1v, h2v, h3v;
            #pragma unroll
            for (int j = 0; j < 8; ++j) {
                float v = x[(b * Dd + c * 8 + j) * 1024 + hw];
                s = fmaf(v, v, s);
                unsigned short h1, h2, h3; split3(-v, h1, h2, h3);   // negated
                h1v[j] = (short)h1; h2v[j] = (short)h2; h3v[j] = (short)h3;
            }
            *(short8*)(xs + (size_t)p * Dd + c * 8) = h1v;
            *(short8*)(xs + PLANE + (size_t)p * Dd + c * 8) = h2v;
            *(short8*)(xs + 2 * PLANE + (size_t)p * Dd + c * 8) = h3v;
        }
        xn2[p] = s;
    }
}

// one 16-codeword tile: 24 MFMAs (2 m-frags x 6 products x 2 ksteps) + argmin.
// chain0 seeded with en = 0.5||e||^2 and A holds -x, so result = en - x.e.
__device__ __forceinline__ void tile_compute(
    const short8 (&a)[2][3][2], const short8 (&b)[6], float en,
    int nb, int l15, float (&bv)[2][4], int (&bi)[2][4])
{
    f32x4 acc[2][2];
    acc[0][0] = f32x4{en, en, en, en}; acc[1][0] = f32x4{en, en, en, en};
    acc[0][1] = f32x4{0.f, 0.f, 0.f, 0.f}; acc[1][1] = f32x4{0.f, 0.f, 0.f, 0.f};
    #define PROD(sx, se) \
        acc[0][0] = __builtin_amdgcn_mfma_f32_16x16x32_bf16(a[0][sx][0], b[(se)*2+0], acc[0][0], 0,0,0); \
        acc[1][0] = __builtin_amdgcn_mfma_f32_16x16x32_bf16(a[1][sx][0], b[(se)*2+0], acc[1][0], 0,0,0); \
        acc[0][1] = __builtin_amdgcn_mfma_f32_16x16x32_bf16(a[0][sx][1], b[(se)*2+1], acc[0][1], 0,0,0); \
        acc[1][1] = __builtin_amdgcn_mfma_f32_16x16x32_bf16(a[1][sx][1], b[(se)*2+1], acc[1][1], 0,0,0);
    PROD(0,0) PROD(0,1) PROD(1,0) PROD(0,2) PROD(1,1) PROD(2,0)
    #undef PROD
    #pragma unroll
    for (int mi = 0; mi < 2; ++mi)
        #pragma unroll
        for (int j = 0; j < 4; ++j) {
            float s = acc[mi][0][j] + acc[mi][1][j];   // en - x.e
            if (s < bv[mi][j]) { bv[mi][j] = s; bi[mi][j] = nb + l15; }
        }
}

// coalesced tiled-fragment load: one base, imm frag offsets
#define LOADB(bf, env, ti) { \
    const short8* tp_ = (const short8*)(es_t + (size_t)(ti) * TILE_USH) + lane; \
    bf[0] = tp_[0];   bf[1] = tp_[64];  bf[2] = tp_[128]; \
    bf[3] = tp_[192]; bf[4] = tp_[256]; bf[5] = tp_[320]; \
    env = en2h[(ti) * 16 + l15]; }

// grid (Nn/128 = 64, KSPLIT=32), block 256 (4 waves). Wave: 32 pixels x 256
// codewords. No LDS/barriers; register double-buffered B prefetch.
// NOTE: 4-wave blocks + (256,3) is the proven no-spill shape (R5). Do NOT
// use single-wave blocks with a min-waves hint (R6: VGPR capped to 48 ->
// scratch spill, 551 MB writes, 6x slowdown).
__global__ __launch_bounds__(256, 3) void dist_mfma(
    const unsigned short* __restrict__ xs, const unsigned short* __restrict__ es_t,
    const float* __restrict__ en2h,
    float* __restrict__ pval, int* __restrict__ pidx)
{
    const int tid = threadIdx.x;
    const int w = tid >> 6, lane = tid & 63;
    const int l15 = lane & 15, kg = lane >> 4;
    const int m0 = blockIdx.x * 128 + w * 32;
    const int t0 = blockIdx.y * NT;           // first tile of this strip

    short8 a[2][3][2];
    #pragma unroll
    for (int mi = 0; mi < 2; ++mi) {
        const unsigned short* xp = xs + (size_t)(m0 + mi * 16 + l15) * Dd + kg * 8;
        #pragma unroll
        for (int s = 0; s < 3; ++s)
            #pragma unroll
            for (int ks = 0; ks < 2; ++ks)
                a[mi][s][ks] = *(const short8*)(xp + s * PLANE + ks * 32);
    }

    float bv[2][4]; int bi[2][4];
    #pragma unroll
    for (int mi = 0; mi < 2; ++mi)
        #pragma unroll
        for (int j = 0; j < 4; ++j) { bv[mi][j] = FLT_MAX; bi[mi][j] = 0; }

    short8 bA[6], bB[6]; float enA, enB;
    LOADB(bA, enA, t0)
    #pragma unroll 1
    for (int nt = 0; nt < NT; nt += 2) {
        const int ti = t0 + nt;
        LOADB(bB, enB, ti + 1)                        // prefetch odd tile
        tile_compute(a, bA, enA, ti * 16, l15, bv, bi);
        if (nt + 2 < NT) { LOADB(bA, enA, ti + 2) }   // prefetch next even tile
        tile_compute(a, bB, enB, ti * 16 + 16, l15, bv, bi);
    }

    #pragma unroll
    for (int m = 1; m < 16; m <<= 1) {
        #pragma unroll
        for (int mi = 0; mi < 2; ++mi)
            #pragma unroll
            for (int j = 0; j < 4; ++j) {
                float ov = __shfl_xor(bv[mi][j], m, 64);
                int   oi = __shfl_xor(bi[mi][j], m, 64);
                if (ov < bv[mi][j] || (ov == bv[mi][j] && oi < bi[mi][j])) {
                    bv[mi][j] = ov; bi[mi][j] = oi;
                }
            }
    }
    if (l15 == 0) {
        #pragma unroll
        for (int mi = 0; mi < 2; ++mi)
            #pragma unroll
            for (int j = 0; j < 4; ++j) {
                int pix = m0 + mi * 16 + kg * 4 + j;
                pval[(size_t)pix * KSPLIT + blockIdx.y] = bv[mi][j];
                pidx[(size_t)pix * KSPLIT + blockIdx.y] = bi[mi][j];
            }
    }
}

// ---- final argmin + rotation trick (affine form qd = cx*x + cq*q) ----
// grid (32, 2): 256 pixels per block, 32 d's per blockIdx.y
__global__ __launch_bounds__(256) void finalize_kernel(
    const float* __restrict__ x, const float* __restrict__ et,
    const float* __restrict__ en2h, const float* __restrict__ xn2,
    const float* __restrict__ pval, const int* __restrict__ pidx,
    float* __restrict__ out_qd, float* __restrict__ out_q, float* __restrict__ out_ind)
{
    const int tid = threadIdx.x;
    const int p = blockIdx.x * 256 + tid;

    // partials are KSPLIT consecutive per pixel -> vectorized float4/int4 reads
    const float4* pv4 = (const float4*)(pval + (size_t)p * KSPLIT);
    const int4*   pi4 = (const int4*)(pidx + (size_t)p * KSPLIT);
    float bvv = FLT_MAX; int bii = 0;
    #pragma unroll
    for (int u = 0; u < KSPLIT / 4; ++u) {
        float4 v4 = pv4[u]; int4 i4 = pi4[u];
        #pragma unroll
        for (int jj = 0; jj < 4; ++jj) {
            float v = ((const float*)&v4)[jj];
            int   i = ((const int*)&i4)[jj];
            if (v < bvv || (v == bvv && i < bii)) { bvv = v; bii = i; }
        }
    }
    if (blockIdx.y == 0) out_ind[p] = (float)bii;

    float sx2 = xn2[p];
    float enh = en2h[bii];
    float sq2 = 2.f * enh;            // ||q||^2
    float sxq = enh - bvv;            // x.q recovered from winning score
    float ne = sqrtf(sx2), nq = sqrtf(sq2);
    float inv_e = 1.f / (ne + EPS), inv_q = 1.f / (nq + EPS);
    float lmbda = (nq + EPS) * inv_e;
    float ehat_dot_e = sx2 * inv_e;
    float rn2 = sx2 * inv_e * inv_e + 2.f * sxq * inv_e * inv_q + sq2 * inv_q * inv_q;
    float inv_r = rsqrtf(rn2);
    float rde = (sx2 * inv_e + sxq * inv_q) * inv_r;
    float cx = lmbda * (1.f - 2.f * rde * inv_r * inv_e);
    float cq = 2.f * lmbda * inv_q * (ehat_dot_e - rde * inv_r);

    const int b = p >> 10, hw = p & 1023;
    const int d0 = blockIdx.y * 32;
    const float* xb = x + (b * Dd + d0) * 1024 + hw;
    const float* er = et + (size_t)bii * Dd + d0;   // consecutive per thread
    float* qd_b = out_qd + (b * Dd + d0) * 1024 + hw;
    float* q_b  = out_q  + (b * Dd + d0) * 1024 + hw;
    #pragma unroll
    for (int dv = 0; dv < 8; ++dv) {
        float4 q4 = *(const float4*)(er + dv * 4);
        #pragma unroll
        for (int jj = 0; jj < 4; ++jj) {
            int d = dv * 4 + jj;
            float xv = xb[d * 1024];
            float qv = ((const float*)&q4)[jj];
            qd_b[d * 1024] = cx * xv + cq * qv;
            q_b[d * 1024]  = qv;
        }
    }
}

extern "C" void kernel_launch(void* const* d_in, const int* in_sizes, int n_in,
                              void* d_out, int out_size, void* d_ws, size_t ws_size,
                              hipStream_t stream) {
    const float* x = (const float*)d_in[0];   // (8,64,32,32)
    const float* e = (const float*)d_in[1];   // (64,8192)
    float* out = (float*)d_out;
    float* out_qd  = out;
    float* out_q   = out + Nn * Dd;
    float* out_ind = out + 2 * Nn * Dd;

    unsigned short* xs   = (unsigned short*)d_ws;          // 3*PLANE ushort (3 MB)
    unsigned short* es_t = xs + 3 * PLANE;                 // 512*3072 ushort (3 MB)
    float* et   = (float*)(es_t + (size_t)(Kk / 16) * TILE_USH);  // Kk*Dd f32 (2 MB)
    float* en2h = et + (size_t)Kk * Dd;                    // Kk f32
    float* xn2  = en2h + Kk;                               // Nn f32
    float* pval = xn2 + Nn;                                // Nn*KSPLIT f32 (1 MB)
    int*   pidx = (int*)(pval + (size_t)Nn * KSPLIT);      // Nn*KSPLIT i32 (1 MB)

    prep_kernel<<<64, 256, 0, stream>>>(e, x, es_t, en2h, et, xs, xn2);
    dist_mfma<<<dim3(Nn / 128, KSPLIT), 256, 0, stream>>>(xs, es_t, en2h, pval, pidx);
    finalize_kernel<<<dim3(32, 2), 256, 0, stream>>>(x, et, en2h, xn2, pval, pidx,
                                                     out_qd, out_q, out_ind);
}

// Round 8
// 66.739 us; speedup vs baseline: 4.5635x; 1.0924x over previous
//
#include <hip/hip_runtime.h>
#include <float.h>
#include <math.h>

#define EPS 1e-6f

typedef __attribute__((ext_vector_type(8))) short short8;   // 8 bf16 = 4 VGPR
typedef __attribute__((ext_vector_type(4))) float f32x4;

constexpr int Nn = 8192;   // B*H*W
constexpr int Dd = 64;
constexpr int Kk = 8192;
constexpr int PLANE = Nn * Dd;
constexpr int KSPLIT = 16;
constexpr int KPB = Kk / KSPLIT;          // 512 codewords per strip
constexpr int NT = KPB / 16;              // 32 tiles per strip
constexpr int TILE_USH = 6 * 64 * 8;      // 3072 ushort per 16-codeword tile

// exact 3-way bf16 split: v == f(h1)+f(h2)+f(h3) (24 mantissa bits, lossless)
__device__ __forceinline__ void split3(float v, unsigned short& h1, unsigned short& h2, unsigned short& h3) {
    unsigned u = __float_as_uint(v);
    h1 = (unsigned short)(u >> 16);
    float r1 = v - __uint_as_float((unsigned)h1 << 16);
    h2 = (unsigned short)(__float_as_uint(r1) >> 16);
    float r2 = r1 - __uint_as_float((unsigned)h2 << 16);
    h3 = (unsigned short)(__float_as_uint(r2) >> 16);
}

// ---- prep ----
// e -> es_t tiled-fragment layout + en2h + et (fp32 [k][d] transpose)
// x -> xs row-major planes (NEGATED splits, so MFMA accumulates -x.e) + xn2
__global__ void prep_kernel(const float* __restrict__ e, const float* __restrict__ x,
                            unsigned short* __restrict__ es_t, float* __restrict__ en2h,
                            float* __restrict__ et,
                            unsigned short* __restrict__ xs, float* __restrict__ xn2)
{
    const int tid = threadIdx.x;
    if (blockIdx.x < 32) {
        const int k = blockIdx.x * 256 + tid;
        const int t = k >> 4, l15 = k & 15;
        unsigned short* tb = es_t + (size_t)t * TILE_USH;
        float s = 0.f;
        #pragma unroll
        for (int c = 0; c < 8; ++c) {          // c = ks*4 + kg ; d = c*8 + j
            const int ks = c >> 2, kg = c & 3;
            short8 h1v, h2v, h3v;
            float fv[8];
            #pragma unroll
            for (int j = 0; j < 8; ++j) {
                float v = e[(c * 8 + j) * Kk + k];
                fv[j] = v;
                s = fmaf(v, v, s);
                unsigned short h1, h2, h3; split3(v, h1, h2, h3);
                h1v[j] = (short)h1; h2v[j] = (short)h2; h3v[j] = (short)h3;
            }
            const int lofs = (kg * 16 + l15) * 8;
            *(short8*)(tb + (0 * 2 + ks) * 512 + lofs) = h1v;
            *(short8*)(tb + (1 * 2 + ks) * 512 + lofs) = h2v;
            *(short8*)(tb + (2 * 2 + ks) * 512 + lofs) = h3v;
            *(float4*)(et + (size_t)k * Dd + c * 8)     = *(float4*)&fv[0];
            *(float4*)(et + (size_t)k * Dd + c * 8 + 4) = *(float4*)&fv[4];
        }
        en2h[k] = 0.5f * s;
    } else {
        const int p = (blockIdx.x - 32) * 256 + tid;
        const int b = p >> 10, hw = p & 1023;
        float s = 0.f;
        #pragma unroll
        for (int c = 0; c < 8; ++c) {
            short8 h1v, h2v, h3v;
            #pragma unroll
            for (int j = 0; j < 8; ++j) {
                float v = x[(b * Dd + c * 8 + j) * 1024 + hw];
                s = fmaf(v, v, s);
                unsigned short h1, h2, h3; split3(-v, h1, h2, h3);   // negated
                h1v[j] = (short)h1; h2v[j] = (short)h2; h3v[j] = (short)h3;
            }
            *(short8*)(xs + (size_t)p * Dd + c * 8) = h1v;
            *(short8*)(xs + PLANE + (size_t)p * Dd + c * 8) = h2v;
            *(short8*)(xs + 2 * PLANE + (size_t)p * Dd + c * 8) = h3v;
        }
        xn2[p] = s;
    }
}

// one 16-codeword tile: 24 MFMAs (2 m-frags x 6 products x 2 ksteps) + argmin.
// chain0 seeded with en = 0.5||e||^2 and A holds -x, so result = en - x.e.
// b must be indexed with compile-time constants only (stays in VGPRs).
__device__ __forceinline__ void tile_compute(
    const short8 (&a)[2][3][2], const short8* b, float en,
    int nb, int l15, float (&bv)[2][4], int (&bi)[2][4])
{
    f32x4 acc[2][2];
    acc[0][0] = f32x4{en, en, en, en}; acc[1][0] = f32x4{en, en, en, en};
    acc[0][1] = f32x4{0.f, 0.f, 0.f, 0.f}; acc[1][1] = f32x4{0.f, 0.f, 0.f, 0.f};
    #define PROD(sx, se) \
        acc[0][0] = __builtin_amdgcn_mfma_f32_16x16x32_bf16(a[0][sx][0], b[(se)*2+0], acc[0][0], 0,0,0); \
        acc[1][0] = __builtin_amdgcn_mfma_f32_16x16x32_bf16(a[1][sx][0], b[(se)*2+0], acc[1][0], 0,0,0); \
        acc[0][1] = __builtin_amdgcn_mfma_f32_16x16x32_bf16(a[0][sx][1], b[(se)*2+1], acc[0][1], 0,0,0); \
        acc[1][1] = __builtin_amdgcn_mfma_f32_16x16x32_bf16(a[1][sx][1], b[(se)*2+1], acc[1][1], 0,0,0);
    PROD(0,0) PROD(0,1) PROD(1,0) PROD(0,2) PROD(1,1) PROD(2,0)
    #undef PROD
    #pragma unroll
    for (int mi = 0; mi < 2; ++mi)
        #pragma unroll
        for (int j = 0; j < 4; ++j) {
            float s = acc[mi][0][j] + acc[mi][1][j];   // en - x.e
            if (s < bv[mi][j]) { bv[mi][j] = s; bi[mi][j] = nb + l15; }
        }
}

// load TWO consecutive tiles (12 fragments) + their en values; tile stride in
// short8 units = TILE_USH/8 = 384
#define LOADB2(bf, e0, e1, ti) { \
    const short8* p0_ = (const short8*)(es_t + (size_t)(ti) * TILE_USH) + lane; \
    bf[0] = p0_[0];   bf[1] = p0_[64];  bf[2]  = p0_[128]; \
    bf[3] = p0_[192]; bf[4] = p0_[256]; bf[5]  = p0_[320]; \
    bf[6] = p0_[384]; bf[7] = p0_[448]; bf[8]  = p0_[512]; \
    bf[9] = p0_[576]; bf[10] = p0_[640]; bf[11] = p0_[704]; \
    e0 = en2h[(ti) * 16 + l15]; e1 = en2h[(ti) * 16 + 16 + l15]; }

// grid (Nn/128 = 64, KSPLIT=16), block 256 (4 waves). Wave: 32 pixels x 512
// codewords. No LDS/barriers. 2-tile-deep register prefetch, pinned by
// sched_barrier so the allocator cannot serialize it (R5/R7: VGPR=80 proved
// the compiler was collapsing the double buffer -> exposed L2 latency).
// NOTE: do NOT set a high min-waves hint (R6: VGPR capped to 48 -> spill).
__global__ __launch_bounds__(256, 2) void dist_mfma(
    const unsigned short* __restrict__ xs, const unsigned short* __restrict__ es_t,
    const float* __restrict__ en2h,
    float* __restrict__ pval, int* __restrict__ pidx)
{
    const int tid = threadIdx.x;
    const int w = tid >> 6, lane = tid & 63;
    const int l15 = lane & 15, kg = lane >> 4;
    const int m0 = blockIdx.x * 128 + w * 32;
    const int t0 = blockIdx.y * NT;           // first tile of this strip

    short8 a[2][3][2];
    #pragma unroll
    for (int mi = 0; mi < 2; ++mi) {
        const unsigned short* xp = xs + (size_t)(m0 + mi * 16 + l15) * Dd + kg * 8;
        #pragma unroll
        for (int s = 0; s < 3; ++s)
            #pragma unroll
            for (int ks = 0; ks < 2; ++ks)
                a[mi][s][ks] = *(const short8*)(xp + s * PLANE + ks * 32);
    }

    float bv[2][4]; int bi[2][4];
    #pragma unroll
    for (int mi = 0; mi < 2; ++mi)
        #pragma unroll
        for (int j = 0; j < 4; ++j) { bv[mi][j] = FLT_MAX; bi[mi][j] = 0; }

    short8 bA[12], bB[12]; float enA0, enA1, enB0, enB1;
    LOADB2(bA, enA0, enA1, t0)
    __builtin_amdgcn_sched_barrier(0);
    #pragma unroll 1
    for (int j = 0; j < NT / 4; ++j) {
        const int ti = t0 + j * 4;
        LOADB2(bB, enB0, enB1, ti + 2)                 // prefetch tiles +2,+3
        __builtin_amdgcn_sched_barrier(0);
        tile_compute(a, &bA[0], enA0, (ti + 0) * 16, l15, bv, bi);
        tile_compute(a, &bA[6], enA1, (ti + 1) * 16, l15, bv, bi);
        if (j + 1 < NT / 4) {
            LOADB2(bA, enA0, enA1, ti + 4)             // prefetch tiles +4,+5
            __builtin_amdgcn_sched_barrier(0);
        }
        tile_compute(a, &bB[0], enB0, (ti + 2) * 16, l15, bv, bi);
        tile_compute(a, &bB[6], enB1, (ti + 3) * 16, l15, bv, bi);
    }

    #pragma unroll
    for (int m = 1; m < 16; m <<= 1) {
        #pragma unroll
        for (int mi = 0; mi < 2; ++mi)
            #pragma unroll
            for (int j = 0; j < 4; ++j) {
                float ov = __shfl_xor(bv[mi][j], m, 64);
                int   oi = __shfl_xor(bi[mi][j], m, 64);
                if (ov < bv[mi][j] || (ov == bv[mi][j] && oi < bi[mi][j])) {
                    bv[mi][j] = ov; bi[mi][j] = oi;
                }
            }
    }
    if (l15 == 0) {
        #pragma unroll
        for (int mi = 0; mi < 2; ++mi)
            #pragma unroll
            for (int j = 0; j < 4; ++j) {
                int pix = m0 + mi * 16 + kg * 4 + j;
                pval[(size_t)pix * KSPLIT + blockIdx.y] = bv[mi][j];
                pidx[(size_t)pix * KSPLIT + blockIdx.y] = bi[mi][j];
            }
    }
}

// ---- final argmin + rotation trick (affine form qd = cx*x + cq*q) ----
// grid (32, 8): 256 pixels per block, 8 d's per blockIdx.y
__global__ __launch_bounds__(256) void finalize_kernel(
    const float* __restrict__ x, const float* __restrict__ et,
    const float* __restrict__ en2h, const float* __restrict__ xn2,
    const float* __restrict__ pval, const int* __restrict__ pidx,
    float* __restrict__ out_qd, float* __restrict__ out_q, float* __restrict__ out_ind)
{
    const int tid = threadIdx.x;
    const int p = blockIdx.x * 256 + tid;

    // partials are KSPLIT consecutive per pixel -> vectorized float4/int4 reads
    const float4* pv4 = (const float4*)(pval + (size_t)p * KSPLIT);
    const int4*   pi4 = (const int4*)(pidx + (size_t)p * KSPLIT);
    float bvv = FLT_MAX; int bii = 0;
    #pragma unroll
    for (int u = 0; u < KSPLIT / 4; ++u) {
        float4 v4 = pv4[u]; int4 i4 = pi4[u];
        #pragma unroll
        for (int jj = 0; jj < 4; ++jj) {
            float v = ((const float*)&v4)[jj];
            int   i = ((const int*)&i4)[jj];
            if (v < bvv || (v == bvv && i < bii)) { bvv = v; bii = i; }
        }
    }
    if (blockIdx.y == 0) out_ind[p] = (float)bii;

    float sx2 = xn2[p];
    float enh = en2h[bii];
    float sq2 = 2.f * enh;            // ||q||^2
    float sxq = enh - bvv;            // x.q recovered from winning score
    float ne = sqrtf(sx2), nq = sqrtf(sq2);
    float inv_e = 1.f / (ne + EPS), inv_q = 1.f / (nq + EPS);
    float lmbda = (nq + EPS) * inv_e;
    float ehat_dot_e = sx2 * inv_e;
    float rn2 = sx2 * inv_e * inv_e + 2.f * sxq * inv_e * inv_q + sq2 * inv_q * inv_q;
    float inv_r = rsqrtf(rn2);
    float rde = (sx2 * inv_e + sxq * inv_q) * inv_r;
    float cx = lmbda * (1.f - 2.f * rde * inv_r * inv_e);
    float cq = 2.f * lmbda * inv_q * (ehat_dot_e - rde * inv_r);

    const int b = p >> 10, hw = p & 1023;
    const int d0 = blockIdx.y * 8;
    const float* xb = x + (b * Dd + d0) * 1024 + hw;
    const float* er = et + (size_t)bii * Dd + d0;   // consecutive per thread
    float* qd_b = out_qd + (b * Dd + d0) * 1024 + hw;
    float* q_b  = out_q  + (b * Dd + d0) * 1024 + hw;
    #pragma unroll
    for (int dv = 0; dv < 2; ++dv) {
        float4 q4 = *(const float4*)(er + dv * 4);
        #pragma unroll
        for (int jj = 0; jj < 4; ++jj) {
            int d = dv * 4 + jj;
            float xv = xb[d * 1024];
            float qv = ((const float*)&q4)[jj];
            qd_b[d * 1024] = cx * xv + cq * qv;
            q_b[d * 1024]  = qv;
        }
    }
}

extern "C" void kernel_launch(void* const* d_in, const int* in_sizes, int n_in,
                              void* d_out, int out_size, void* d_ws, size_t ws_size,
                              hipStream_t stream) {
    const float* x = (const float*)d_in[0];   // (8,64,32,32)
    const float* e = (const float*)d_in[1];   // (64,8192)
    float* out = (float*)d_out;
    float* out_qd  = out;
    float* out_q   = out + Nn * Dd;
    float* out_ind = out + 2 * Nn * Dd;

    unsigned short* xs   = (unsigned short*)d_ws;          // 3*PLANE ushort (3 MB)
    unsigned short* es_t = xs + 3 * PLANE;                 // 512*3072 ushort (3 MB)
    float* et   = (float*)(es_t + (size_t)(Kk / 16) * TILE_USH);  // Kk*Dd f32 (2 MB)
    float* en2h = et + (size_t)Kk * Dd;                    // Kk f32
    float* xn2  = en2h + Kk;                               // Nn f32
    float* pval = xn2 + Nn;                                // Nn*KSPLIT f32
    int*   pidx = (int*)(pval + (size_t)Nn * KSPLIT);      // Nn*KSPLIT i32

    prep_kernel<<<64, 256, 0, stream>>>(e, x, es_t, en2h, et, xs, xn2);
    dist_mfma<<<dim3(Nn / 128, KSPLIT), 256, 0, stream>>>(xs, es_t, en2h, pval, pidx);
    finalize_kernel<<<dim3(32, 8), 256, 0, stream>>>(x, et, en2h, xn2, pval, pidx,
                                                     out_qd, out_q, out_ind);
}

// Round 9
// 64.119 us; speedup vs baseline: 4.7500x; 1.0409x over previous
//
#include <hip/hip_runtime.h>
#include <float.h>
#include <math.h>

#define EPS 1e-6f

typedef __attribute__((ext_vector_type(8))) short short8;   // 8 bf16 = 4 VGPR
typedef __attribute__((ext_vector_type(4))) float f32x4;

constexpr int Nn = 8192;   // B*H*W
constexpr int Dd = 64;
constexpr int Kk = 8192;
constexpr int PLANE = Nn * Dd;
constexpr int KSPLIT = 8;
constexpr int KPB = Kk / KSPLIT;          // 1024 codewords per strip
constexpr int NT = KPB / 16;              // 64 tiles per strip
constexpr int NPAIR = NT / 2;             // 32 tile-pairs per strip
constexpr int TILE_USH = 6 * 64 * 8;      // 3072 ushort per 16-codeword tile
constexpr int TILE_BYTES = TILE_USH * 2;  // 6144 B

// exact 3-way bf16 split: v == f(h1)+f(h2)+f(h3) (24 mantissa bits, lossless)
__device__ __forceinline__ void split3(float v, unsigned short& h1, unsigned short& h2, unsigned short& h3) {
    unsigned u = __float_as_uint(v);
    h1 = (unsigned short)(u >> 16);
    float r1 = v - __uint_as_float((unsigned)h1 << 16);
    h2 = (unsigned short)(__float_as_uint(r1) >> 16);
    float r2 = r1 - __uint_as_float((unsigned)h2 << 16);
    h3 = (unsigned short)(__float_as_uint(r2) >> 16);
}

typedef __attribute__((address_space(3))) unsigned int lds_u32_t;
typedef __attribute__((address_space(1))) unsigned int glb_u32_t;
// async global->LDS, 16B per lane; lds dest = uniform base + lane*16
__device__ __forceinline__ void gload_lds16(const void* g, void* l) {
    __builtin_amdgcn_global_load_lds((const glb_u32_t*)g, (lds_u32_t*)l, 16, 0, 0);
}

// ---- prep ----
// e -> es_t tiled-fragment layout + en2h + et (fp32 [k][d] transpose)
// x -> xs row-major planes (NEGATED splits, so MFMA accumulates -x.e) + xn2
__global__ void prep_kernel(const float* __restrict__ e, const float* __restrict__ x,
                            unsigned short* __restrict__ es_t, float* __restrict__ en2h,
                            float* __restrict__ et,
                            unsigned short* __restrict__ xs, float* __restrict__ xn2)
{
    const int tid = threadIdx.x;
    if (blockIdx.x < 32) {
        const int k = blockIdx.x * 256 + tid;
        const int t = k >> 4, l15 = k & 15;
        unsigned short* tb = es_t + (size_t)t * TILE_USH;
        float s = 0.f;
        #pragma unroll
        for (int c = 0; c < 8; ++c) {          // c = ks*4 + kg ; d = c*8 + j
            const int ks = c >> 2, kg = c & 3;
            short8 h1v, h2v, h3v;
            float fv[8];
            #pragma unroll
            for (int j = 0; j < 8; ++j) {
                float v = e[(c * 8 + j) * Kk + k];
                fv[j] = v;
                s = fmaf(v, v, s);
                unsigned short h1, h2, h3; split3(v, h1, h2, h3);
                h1v[j] = (short)h1; h2v[j] = (short)h2; h3v[j] = (short)h3;
            }
            const int lofs = (kg * 16 + l15) * 8;
            *(short8*)(tb + (0 * 2 + ks) * 512 + lofs) = h1v;
            *(short8*)(tb + (1 * 2 + ks) * 512 + lofs) = h2v;
            *(short8*)(tb + (2 * 2 + ks) * 512 + lofs) = h3v;
            *(float4*)(et + (size_t)k * Dd + c * 8)     = *(float4*)&fv[0];
            *(float4*)(et + (size_t)k * Dd + c * 8 + 4) = *(float4*)&fv[4];
        }
        en2h[k] = 0.5f * s;
    } else {
        const int p = (blockIdx.x - 32) * 256 + tid;
        const int b = p >> 10, hw = p & 1023;
        float s = 0.f;
        #pragma unroll
        for (int c = 0; c < 8; ++c) {
            short8 h1v, h2v, h3v;
            #pragma unroll
            for (int j = 0; j < 8; ++j) {
                float v = x[(b * Dd + c * 8 + j) * 1024 + hw];
                s = fmaf(v, v, s);
                unsigned short h1, h2, h3; split3(-v, h1, h2, h3);   // negated
                h1v[j] = (short)h1; h2v[j] = (short)h2; h3v[j] = (short)h3;
            }
            *(short8*)(xs + (size_t)p * Dd + c * 8) = h1v;
            *(short8*)(xs + PLANE + (size_t)p * Dd + c * 8) = h2v;
            *(short8*)(xs + 2 * PLANE + (size_t)p * Dd + c * 8) = h3v;
        }
        xn2[p] = s;
    }
}

// one 16-codeword tile: 24 MFMAs (2 m-frags x 6 products x 2 ksteps) + argmin.
// chain0 seeded with en = 0.5||e||^2 and A holds -x, so result = en - x.e.
__device__ __forceinline__ void tile_compute(
    const short8 (&a)[2][3][2], const short8 (&b)[6], float en,
    int nb, int l15, float (&bv)[2][4], int (&bi)[2][4])
{
    f32x4 acc[2][2];
    acc[0][0] = f32x4{en, en, en, en}; acc[1][0] = f32x4{en, en, en, en};
    acc[0][1] = f32x4{0.f, 0.f, 0.f, 0.f}; acc[1][1] = f32x4{0.f, 0.f, 0.f, 0.f};
    #define PROD(sx, se) \
        acc[0][0] = __builtin_amdgcn_mfma_f32_16x16x32_bf16(a[0][sx][0], b[(se)*2+0], acc[0][0], 0,0,0); \
        acc[1][0] = __builtin_amdgcn_mfma_f32_16x16x32_bf16(a[1][sx][0], b[(se)*2+0], acc[1][0], 0,0,0); \
        acc[0][1] = __builtin_amdgcn_mfma_f32_16x16x32_bf16(a[0][sx][1], b[(se)*2+1], acc[0][1], 0,0,0); \
        acc[1][1] = __builtin_amdgcn_mfma_f32_16x16x32_bf16(a[1][sx][1], b[(se)*2+1], acc[1][1], 0,0,0);
    PROD(0,0) PROD(0,1) PROD(1,0) PROD(0,2) PROD(1,1) PROD(2,0)
    #undef PROD
    #pragma unroll
    for (int mi = 0; mi < 2; ++mi)
        #pragma unroll
        for (int j = 0; j < 4; ++j) {
            float s = acc[mi][0][j] + acc[mi][1][j];   // en - x.e
            if (s < bv[mi][j]) { bv[mi][j] = s; bi[mi][j] = nb + l15; }
        }
}

// grid (Nn/128 = 64, KSPLIT=8), block 256 (4 waves). Block: 128 pixels x 1024
// codewords. B tiles staged ONCE per block into LDS via global_load_lds and
// shared by all 4 waves (R8 was L2-BW-bound at ~15.5 TB/s from 4x redundant
// per-wave B streams; LDS sharing cuts L2 traffic 4x).
// NOTE: do NOT set a tight min-waves hint (R6: VGPR capped to 48 -> spill).
__global__ __launch_bounds__(256, 2) void dist_mfma(
    const unsigned short* __restrict__ xs, const unsigned short* __restrict__ es_t,
    const float* __restrict__ en2h,
    float* __restrict__ pval, int* __restrict__ pidx)
{
    __shared__ __align__(16) unsigned short sB[2][2 * TILE_USH];  // 2 x 12 KB

    const int tid = threadIdx.x;
    const int w = tid >> 6, lane = tid & 63;
    const int l15 = lane & 15, kg = lane >> 4;
    const int m0 = blockIdx.x * 128 + w * 32;
    const int t0 = blockIdx.y * NT;           // first tile of this strip

    // A fragments (resident): 2 m-frags x 3 splits x 2 ksteps
    short8 a[2][3][2];
    #pragma unroll
    for (int mi = 0; mi < 2; ++mi) {
        const unsigned short* xp = xs + (size_t)(m0 + mi * 16 + l15) * Dd + kg * 8;
        #pragma unroll
        for (int s = 0; s < 3; ++s)
            #pragma unroll
            for (int ks = 0; ks < 2; ++ks)
                a[mi][s][ks] = *(const short8*)(xp + s * PLANE + ks * 32);
    }

    float bv[2][4]; int bi[2][4];
    #pragma unroll
    for (int mi = 0; mi < 2; ++mi)
        #pragma unroll
        for (int j = 0; j < 4; ++j) { bv[mi][j] = FLT_MAX; bi[mi][j] = 0; }

    // stage tile-pair pi (12 KB contiguous in es_t) into sB[buf]:
    // wave w stages 3 chunks of 1 KB at offsets r*4096 + w*1024
    #define STAGE_PAIR(buf, pi) { \
        const char* gb_ = (const char*)es_t + (size_t)(pi) * (2 * TILE_BYTES); \
        char* lb_ = (char*)&sB[buf][0]; \
        _Pragma("unroll") \
        for (int r_ = 0; r_ < 3; ++r_) { \
            const int off_ = r_ * 4096 + w * 1024; \
            gload_lds16(gb_ + off_ + lane * 16, lb_ + off_); } }

    STAGE_PAIR(0, t0 / 2)
    __syncthreads();

    #pragma unroll 1
    for (int p = 0; p < NPAIR; ++p) {
        const int cur = p & 1;
        if (p + 1 < NPAIR) { STAGE_PAIR(cur ^ 1, t0 / 2 + p + 1) }

        const int ti = t0 + p * 2;
        float en0 = en2h[ti * 16 + l15];
        float en1 = en2h[ti * 16 + 16 + l15];

        // ds_read both tiles' fragments (linear lane*16B layout: conflict-free)
        short8 bf0[6], bf1[6];
        {
            const unsigned short* lb = &sB[cur][lane * 8];
            #pragma unroll
            for (int f = 0; f < 6; ++f) bf0[f] = *(const short8*)(lb + f * 512);
            #pragma unroll
            for (int f = 0; f < 6; ++f) bf1[f] = *(const short8*)(lb + TILE_USH + f * 512);
        }
        tile_compute(a, bf0, en0, ti * 16, l15, bv, bi);
        tile_compute(a, bf1, en1, ti * 16 + 16, l15, bv, bi);

        __syncthreads();   // staging of next pair complete; all waves done with cur
    }

    #pragma unroll
    for (int m = 1; m < 16; m <<= 1) {
        #pragma unroll
        for (int mi = 0; mi < 2; ++mi)
            #pragma unroll
            for (int j = 0; j < 4; ++j) {
                float ov = __shfl_xor(bv[mi][j], m, 64);
                int   oi = __shfl_xor(bi[mi][j], m, 64);
                if (ov < bv[mi][j] || (ov == bv[mi][j] && oi < bi[mi][j])) {
                    bv[mi][j] = ov; bi[mi][j] = oi;
                }
            }
    }
    if (l15 == 0) {
        #pragma unroll
        for (int mi = 0; mi < 2; ++mi)
            #pragma unroll
            for (int j = 0; j < 4; ++j) {
                int pix = m0 + mi * 16 + kg * 4 + j;
                pval[(size_t)pix * KSPLIT + blockIdx.y] = bv[mi][j];
                pidx[(size_t)pix * KSPLIT + blockIdx.y] = bi[mi][j];
            }
    }
}

// ---- final argmin + rotation trick (affine form qd = cx*x + cq*q) ----
// grid (32, 8): 256 pixels per block, 8 d's per blockIdx.y
__global__ __launch_bounds__(256) void finalize_kernel(
    const float* __restrict__ x, const float* __restrict__ et,
    const float* __restrict__ en2h, const float* __restrict__ xn2,
    const float* __restrict__ pval, const int* __restrict__ pidx,
    float* __restrict__ out_qd, float* __restrict__ out_q, float* __restrict__ out_ind)
{
    const int tid = threadIdx.x;
    const int p = blockIdx.x * 256 + tid;

    const float4* pv4 = (const float4*)(pval + (size_t)p * KSPLIT);
    const int4*   pi4 = (const int4*)(pidx + (size_t)p * KSPLIT);
    float bvv = FLT_MAX; int bii = 0;
    #pragma unroll
    for (int u = 0; u < KSPLIT / 4; ++u) {
        float4 v4 = pv4[u]; int4 i4 = pi4[u];
        #pragma unroll
        for (int jj = 0; jj < 4; ++jj) {
            float v = ((const float*)&v4)[jj];
            int   i = ((const int*)&i4)[jj];
            if (v < bvv || (v == bvv && i < bii)) { bvv = v; bii = i; }
        }
    }
    if (blockIdx.y == 0) out_ind[p] = (float)bii;

    float sx2 = xn2[p];
    float enh = en2h[bii];
    float sq2 = 2.f * enh;            // ||q||^2
    float sxq = enh - bvv;            // x.q recovered from winning score
    float ne = sqrtf(sx2), nq = sqrtf(sq2);
    float inv_e = 1.f / (ne + EPS), inv_q = 1.f / (nq + EPS);
    float lmbda = (nq + EPS) * inv_e;
    float ehat_dot_e = sx2 * inv_e;
    float rn2 = sx2 * inv_e * inv_e + 2.f * sxq * inv_e * inv_q + sq2 * inv_q * inv_q;
    float inv_r = rsqrtf(rn2);
    float rde = (sx2 * inv_e + sxq * inv_q) * inv_r;
    float cx = lmbda * (1.f - 2.f * rde * inv_r * inv_e);
    float cq = 2.f * lmbda * inv_q * (ehat_dot_e - rde * inv_r);

    const int b = p >> 10, hw = p & 1023;
    const int d0 = blockIdx.y * 8;
    const float* xb = x + (b * Dd + d0) * 1024 + hw;
    const float* er = et + (size_t)bii * Dd + d0;   // consecutive per thread
    float* qd_b = out_qd + (b * Dd + d0) * 1024 + hw;
    float* q_b  = out_q  + (b * Dd + d0) * 1024 + hw;
    #pragma unroll
    for (int dv = 0; dv < 2; ++dv) {
        float4 q4 = *(const float4*)(er + dv * 4);
        #pragma unroll
        for (int jj = 0; jj < 4; ++jj) {
            int d = dv * 4 + jj;
            float xv = xb[d * 1024];
            float qv = ((const float*)&q4)[jj];
            qd_b[d * 1024] = cx * xv + cq * qv;
            q_b[d * 1024]  = qv;
        }
    }
}

extern "C" void kernel_launch(void* const* d_in, const int* in_sizes, int n_in,
                              void* d_out, int out_size, void* d_ws, size_t ws_size,
                              hipStream_t stream) {
    const float* x = (const float*)d_in[0];   // (8,64,32,32)
    const float* e = (const float*)d_in[1];   // (64,8192)
    float* out = (float*)d_out;
    float* out_qd  = out;
    float* out_q   = out + Nn * Dd;
    float* out_ind = out + 2 * Nn * Dd;

    unsigned short* xs   = (unsigned short*)d_ws;          // 3*PLANE ushort (3 MB)
    unsigned short* es_t = xs + 3 * PLANE;                 // 512*3072 ushort (3 MB)
    float* et   = (float*)(es_t + (size_t)(Kk / 16) * TILE_USH);  // Kk*Dd f32 (2 MB)
    float* en2h = et + (size_t)Kk * Dd;                    // Kk f32
    float* xn2  = en2h + Kk;                               // Nn f32
    float* pval = xn2 + Nn;                                // Nn*KSPLIT f32
    int*   pidx = (int*)(pval + (size_t)Nn * KSPLIT);      // Nn*KSPLIT i32

    prep_kernel<<<64, 256, 0, stream>>>(e, x, es_t, en2h, et, xs, xn2);
    dist_mfma<<<dim3(Nn / 128, KSPLIT), 256, 0, stream>>>(xs, es_t, en2h, pval, pidx);
    finalize_kernel<<<dim3(32, 8), 256, 0, stream>>>(x, et, en2h, xn2, pval, pidx,
                                                     out_qd, out_q, out_ind);
}